// Round 3
// baseline (511.841 us; speedup 1.0000x reference)
//
#include <hip/hip_runtime.h>

typedef short short8 __attribute__((ext_vector_type(8)));
typedef float f32x4 __attribute__((ext_vector_type(4)));

union U8 { short8 s8; unsigned int u[4]; };

__device__ __forceinline__ unsigned short f2bf(float f) {
    unsigned int u = __float_as_uint(f);
    u = (u + 0x7fffu + ((u >> 16) & 1u)) >> 16;
    return (unsigned short)u;
}
__device__ __forceinline__ float bf2f(unsigned short s) {
    return __uint_as_float(((unsigned int)s) << 16);
}

// ======== workspace byte offsets ========
// h1p2 : 0          (64,130,2,66,32) bf16  70,287,360 B  -- e1 out, parity-split cols
// h2p  : 70287360   (64,66,66,64)  bf16   35,684,352 B
// zqp  : 139526144  (64,66,66,64)  bf16   35,684,352 B
// d1op : 175210496  (64,66,66,32)  bf16   17,842,176 B
// sc16 : 193052672  (16,64,128,128) bf16  33,554,432 B  -- tap-major d3 scores
// ape2 : 226607104  65536 ; ape3: 226672640 73728 ; apd1: 226746368 36864
// apd2 : 226783232  65536 ; apd3: 226848768 2048  ; embbf: 226850816 65536
// hninit: 226916352 2048

// ---------------- e1 + halo zeroing + weight prep (single launch) ----------------
__global__ __launch_bounds__(256) void k_e1i(
    const float* __restrict__ x, const float* __restrict__ e1w, const float* __restrict__ e1b,
    unsigned short* __restrict__ h1p2, unsigned int* __restrict__ ws_dw,
    const float* __restrict__ e2w, const float* __restrict__ e3w,
    const float* __restrict__ d1w, const float* __restrict__ d2w,
    const float* __restrict__ d3w, const float* __restrict__ emb,
    unsigned short* __restrict__ ape2, unsigned short* __restrict__ ape3,
    unsigned short* __restrict__ apd1, unsigned short* __restrict__ apd2,
    unsigned short* __restrict__ apd3, unsigned short* __restrict__ embbf,
    float* __restrict__ hninit)
{
    int bid = blockIdx.x;
    if (bid < 4096) {
        // ---- e1 conv ----
        int idx = bid * 256 + threadIdx.x;
        int ow = idx & 127, oh = (idx >> 7) & 127, n = idx >> 14;
        const float* xn = x + (size_t)n * 65536;
        float patch[16];
#pragma unroll
        for (int kh = 0; kh < 4; kh++) {
            int ih = 2 * oh + kh - 1;
#pragma unroll
            for (int kw = 0; kw < 4; kw++) {
                int iw = 2 * ow + kw - 1;
                bool ok = ((unsigned)ih < 256u) & ((unsigned)iw < 256u);
                patch[kh * 4 + kw] = ok ? xn[ih * 256 + iw] : 0.f;
            }
        }
        unsigned int outw[16];
#pragma unroll
        for (int oc = 0; oc < 32; oc++) {
            float acc = e1b[oc];
#pragma unroll
            for (int t = 0; t < 16; t++) acc += patch[t] * e1w[oc * 16 + t];
            unsigned short bf = f2bf(fmaxf(acc, 0.f));
            if (oc & 1) outw[oc >> 1] |= ((unsigned int)bf) << 16;
            else        outw[oc >> 1] = bf;
        }
        int par = ow & 1;
        int cidx = (ow + par) >> 1;
        size_t base = ((size_t)((idx >> 14) * 130 + oh + 1) * 2 + par) * 2112 + cidx * 32;
        uint4* dst = (uint4*)(h1p2 + base);
#pragma unroll
        for (int i = 0; i < 4; i++) dst[i] = *(uint4*)&outw[i * 4];
        return;
    }
    if (bid < 11376) {
        // ---- halo zeroing ----
        int t = (bid - 4096) * 256 + threadIdx.x;
        if (t < 270336) {
            int img = t / 4224, q = t % 4224;
            int rowsel = q / 2112, rem = q % 2112;
            ws_dw[img * 274560 + rowsel * 129 * 2112 + rem] = 0u;
        } else if (t < 532480) {
            int g = t - 270336;
            int img = g / 4096, q = g % 4096;
            int row = 1 + (q >> 5), c2 = q & 31;
            int sel = c2 >> 4, ch = c2 & 15;
            int par = sel ? 0 : 1, idx2 = sel ? 64 : 0;
            ws_dw[img * 274560 + row * 2112 + par * 1056 + idx2 * 16 + ch] = 0u;
        } else if (t < 1863680) {
            unsigned int base, Cd, r;
            if (t < 1064960)      { base = 17571840u; Cd = 32; r = t - 532480;  }   // h2p
            else if (t < 1597440) { base = 34881536u; Cd = 32; r = t - 1064960; }   // zqp
            else                  { base = 43802624u; Cd = 16; r = t - 1597440; }   // d1op
            unsigned int per_img = 260u * Cd;
            unsigned int img = r / per_img, q = r % per_img;
            unsigned int p = q / Cd, c = q % Cd;
            unsigned int row, col;
            if (p < 66u)        { row = 0;  col = p; }
            else if (p < 132u)  { row = 65; col = p - 66u; }
            else { unsigned int s = p - 132u; row = 1 + (s >> 1); col = (s & 1) ? 65u : 0u; }
            ws_dw[base + ((img * 66u + row) * 66u + col) * Cd + c] = 0u;
        }
        return;
    }
    // ---- weight prep ----
    int f = (bid - 11376) * 256 + threadIdx.x;
    if (f < 4096) {                               // e2
        int ks = f >> 8, mt = (f >> 6) & 3, lane = f & 63;
        int quad = lane >> 4, l16 = lane & 15;
        int oc = mt * 16 + l16, kh = ks >> 2, kw = ks & 3;
        short8 sv;
#pragma unroll
        for (int j = 0; j < 8; j++) {
            int ic = quad * 8 + j;
            sv[j] = (short)f2bf(e2w[((oc * 32 + ic) * 4 + kh) * 4 + kw]);
        }
        ((short8*)ape2)[f] = sv;
    } else if (f < 8704) {                        // e3
        int g = f - 4096;
        int ks = g >> 8, mt = (g >> 6) & 3, lane = g & 63;
        int quad = lane >> 4, l16 = lane & 15;
        int oc = mt * 16 + l16, tap = ks >> 1, kh = tap / 3, kw = tap % 3;
        int icb = (ks & 1) * 32 + quad * 8;
        short8 sv;
#pragma unroll
        for (int j = 0; j < 8; j++)
            sv[j] = (short)f2bf(e3w[((oc * 64 + icb + j) * 3 + kh) * 3 + kw]);
        ((short8*)ape3)[g] = sv;
    } else if (f < 11008) {                       // d1 (flipped)
        int g = f - 8704;
        int ks = g >> 7, mt = (g >> 6) & 1, lane = g & 63;
        int quad = lane >> 4, l16 = lane & 15;
        int oc = mt * 16 + l16, tap = ks >> 1, kh = tap / 3, kw = tap % 3;
        int icb = (ks & 1) * 32 + quad * 8;
        short8 sv;
#pragma unroll
        for (int j = 0; j < 8; j++)
            sv[j] = (short)f2bf(d1w[(((icb + j) * 32 + oc) * 3 + (2 - kh)) * 3 + (2 - kw)]);
        ((short8*)apd1)[g] = sv;
    } else if (f < 15104) {                       // d2 per parity
        int g = f - 11008;
        int par = g >> 10, ks = (g >> 8) & 3, mt = (g >> 6) & 3, lane = g & 63;
        int quad = lane >> 4, l16 = lane & 15;
        int ph = par >> 1, pw = par & 1, a = ks >> 1, bb = ks & 1;
        int kh = 3 - ph - 2 * a, kw = 3 - pw - 2 * bb;
        int oc = mt * 16 + l16;
        short8 sv;
#pragma unroll
        for (int j = 0; j < 8; j++) {
            int ic = quad * 8 + j;
            sv[j] = (short)f2bf(d2w[((ic * 64 + oc) * 4 + kh) * 4 + kw]);
        }
        ((short8*)apd2)[g] = sv;
    } else if (f < 15232) {                       // d3: A[tap][ic]
        int g = f - 15104;
        int ks = g >> 6, lane = g & 63;
        int quad = lane >> 4, tap = lane & 15;
        short8 sv;
#pragma unroll
        for (int j = 0; j < 8; j++) {
            int ic = ks * 32 + quad * 8 + j;
            sv[j] = (short)f2bf(d3w[ic * 16 + tap]);
        }
        ((short8*)apd3)[g] = sv;
    } else if (f < 19328) {                       // emb bf16
        int g = f - 15232;
        int code = g >> 3, chb = (g & 7) * 8;
        short8 sv;
#pragma unroll
        for (int j = 0; j < 8; j++) sv[j] = (short)f2bf(emb[code * 64 + chb + j]);
        ((short8*)embbf)[g] = sv;
    } else if (f < 19840) {                       // hninit = 2 - 0.5||e||^2
        int code = f - 19328;
        float s = 0.f;
        for (int c = 0; c < 64; c++) { float v = emb[code * 64 + c]; s += v * v; }
        hninit[code] = 2.0f - 0.5f * s;
    }
}

// ---------------- MFMA implicit-GEMM conv ----------------
// MODE 0: e2 (parity-split input)   2: d1
template<int CIN, int COUT, int KSTEPS, int NCH, int WPIN, int MODE>
__global__ __launch_bounds__(256, 4) void k_conv(const unsigned short* __restrict__ inp,
                                                 const unsigned short* __restrict__ aprep,
                                                 const float* __restrict__ bias,
                                                 unsigned short* __restrict__ out0) {
    constexpr int MT = COUT / 16;
    constexpr int KCH = KSTEPS / NCH;
    __shared__ short8 sA[KCH * MT * 64];
    int tid = threadIdx.x;
    int wave = tid >> 6, lane = tid & 63, quad = lane >> 4, l16 = lane & 15;
    int bid = blockIdx.x;
    int n = bid >> 4, rg = bid & 15;
    int oh = rg * 4 + wave;

    int base0;
    if (MODE == 0) base0 = (n * 130 + 2 * oh) * 4224 + quad * 8;
    else           base0 = n * (WPIN * WPIN * CIN) + ((oh + 1) * WPIN + 1) * CIN + quad * 8;

    f32x4 acc[4][MT];
#pragma unroll
    for (int t = 0; t < 4; t++)
#pragma unroll
        for (int mt = 0; mt < MT; mt++)
            acc[t][mt] = *(const f32x4*)(bias + mt * 16 + quad * 4);

#pragma unroll
    for (int ch = 0; ch < NCH; ch++) {
        for (int i = tid; i < KCH * MT * 64; i += 256)
            sA[i] = ((const short8*)aprep)[ch * (KCH * MT * 64) + i];
        __syncthreads();
#pragma unroll
        for (int k = 0; k < KCH; k++) {
            int ks = ch * KCH + k;
            int off, pxs;
            if (MODE == 0) {
                int kh = ks >> 2, kw = ks & 3;
                int par = (kw & 1) ^ 1;
                off = kh * 4224 + par * 2112 + (kw >> 1) * 32;
                pxs = 32;
            } else {
                int tap = ks >> 1, kh = tap / 3, kw = tap % 3;
                off = ((kh - 1) * WPIN + (kw - 1)) * CIN + (ks & 1) * 32;
                pxs = CIN;
            }
            short8 bfr[4];
#pragma unroll
            for (int t = 0; t < 4; t++)
                bfr[t] = *(const short8*)(inp + base0 + (t * 16 + l16) * pxs + off);
#pragma unroll
            for (int mt = 0; mt < MT; mt++) {
                short8 a = sA[(k * MT + mt) * 64 + lane];
#pragma unroll
                for (int t = 0; t < 4; t++)
                    acc[t][mt] = __builtin_amdgcn_mfma_f32_16x16x32_bf16(a, bfr[t], acc[t][mt], 0, 0, 0);
            }
        }
        if (ch + 1 < NCH) __syncthreads();
    }

#pragma unroll
    for (int t = 0; t < 4; t++) {
        int ow = t * 16 + l16;
#pragma unroll
        for (int mt = 0; mt < MT; mt++) {
            float v0 = fmaxf(acc[t][mt][0], 0.f), v1 = fmaxf(acc[t][mt][1], 0.f);
            float v2 = fmaxf(acc[t][mt][2], 0.f), v3 = fmaxf(acc[t][mt][3], 0.f);
            unsigned int lo = (unsigned int)f2bf(v0) | ((unsigned int)f2bf(v1) << 16);
            unsigned int hi = (unsigned int)f2bf(v2) | ((unsigned int)f2bf(v3) << 16);
            uint2 uu; uu.x = lo; uu.y = hi;
            int oc = mt * 16 + quad * 4;
            if (MODE == 0) {
                size_t addr = (size_t)n * 278784 + ((oh + 1) * 66 + ow + 1) * 64 + oc;
                *(uint2*)(out0 + addr) = uu;
            } else {
                size_t addr = (size_t)n * 139392 + ((oh + 1) * 66 + ow + 1) * 32 + oc;
                *(uint2*)(out0 + addr) = uu;
            }
        }
    }
}

// ---------------- e3 conv fused with VQ ----------------
// R3: R1 structure (LDS A-staging, acc[4][4], grid 1024) + code-partitioned VQ.
// The VQ codebook stream is a PER-WAVE fixed cost (64KB L2 per wave regardless of
// tile count) -- R2 proved it: doubling waves doubled the stream and cost +34us.
// Fix: partition CODES across the block's 4 waves (128 codes each, 16KB/wave,
// 256MB -> 64MB L2 traffic); each wave scans all 16 tiles whose B-fragments sit
// in the dead sA LDS region (32KB). Per-pixel packed keys (value|511-code) are
// globally comparable -> 4KB LDS cross-wave max reproduces R1 bit-exactly.
__global__ __launch_bounds__(256, 4) void k_e3vq(const unsigned short* __restrict__ h2p,
                                                 const unsigned short* __restrict__ ape3,
                                                 const float* __restrict__ bias,
                                                 const unsigned short* __restrict__ embbf,
                                                 const float* __restrict__ hninit,
                                                 float* __restrict__ ze_out,
                                                 float* __restrict__ zq_out,
                                                 unsigned short* __restrict__ zqp) {
    __shared__ __align__(16) char smem[36864];
    short8* sA = (short8*)smem;                       // conv phase: 2304 short8 = 36KB
    short8* sB = (short8*)smem;                       // VQ phase:  2048 short8 = 32KB
    unsigned int* cross = (unsigned int*)(smem + 32768);  // 16 tiles * 16 px * 4 waves = 4KB

    int tid = threadIdx.x;
    int wave = tid >> 6, lane = tid & 63, quad = lane >> 4, l16 = lane & 15;
    int bid = blockIdx.x;
    int n = bid >> 4, rg = bid & 15;
    int oh = rg * 4 + wave;
    int base0 = n * 278784 + ((oh + 1) * 66 + 1) * 64 + quad * 8;

    f32x4 acc[4][4];
#pragma unroll
    for (int t = 0; t < 4; t++)
#pragma unroll
        for (int mt = 0; mt < 4; mt++)
            acc[t][mt] = *(const f32x4*)(bias + mt * 16 + quad * 4);

#pragma unroll
    for (int ch = 0; ch < 2; ch++) {
        for (int i = tid; i < 9 * 4 * 64; i += 256)
            sA[i] = ((const short8*)ape3)[ch * (9 * 4 * 64) + i];
        __syncthreads();
#pragma unroll
        for (int k = 0; k < 9; k++) {
            int ks = ch * 9 + k;
            int tap = ks >> 1, kh = tap / 3, kw = tap % 3;
            int off = ((kh - 1) * 66 + (kw - 1)) * 64 + (ks & 1) * 32;
            short8 bfr[4];
#pragma unroll
            for (int t = 0; t < 4; t++)
                bfr[t] = *(const short8*)(h2p + base0 + (t * 16 + l16) * 64 + off);
#pragma unroll
            for (int mt = 0; mt < 4; mt++) {
                short8 a = sA[(k * 4 + mt) * 64 + lane];
#pragma unroll
                for (int t = 0; t < 4; t++)
                    acc[t][mt] = __builtin_amdgcn_mfma_f32_16x16x32_bf16(a, bfr[t], acc[t][mt], 0, 0, 0);
            }
        }
        if (ch == 0) __syncthreads();
    }
    // all waves done reading sA before sB overwrites it
    __syncthreads();

    // relu in place
#pragma unroll
    for (int t = 0; t < 4; t++)
#pragma unroll
        for (int mt = 0; mt < 4; mt++)
#pragma unroll
            for (int r = 0; r < 4; r++)
                acc[t][mt][r] = fmaxf(acc[t][mt][r], 0.f);

    // ze fp32 NCHW (graded output), nontemporal
#pragma unroll
    for (int t = 0; t < 4; t++) {
        int px = oh * 64 + t * 16 + l16;
#pragma unroll
        for (int mt = 0; mt < 4; mt++) {
            int oc = mt * 16 + quad * 4;
#pragma unroll
            for (int r = 0; r < 4; r++)
                __builtin_nontemporal_store(acc[t][mt][r], &ze_out[((size_t)n * 64 + oc + r) * 4096 + px]);
        }
    }

    // in-register C-layout -> B-layout transform (8 shfl per tile), stash in LDS
    int s0 = (((2 * quad) & 3) << 4) | l16;
    int s1 = (((2 * quad + 1) & 3) << 4) | l16;
#pragma unroll
    for (int t = 0; t < 4; t++) {
        f32x4 xv = (quad < 2) ? acc[t][0] : acc[t][1];
        f32x4 yv = (quad < 2) ? acc[t][2] : acc[t][3];
        unsigned int xa = (unsigned int)f2bf(xv[0]) | ((unsigned int)f2bf(xv[1]) << 16);
        unsigned int xb = (unsigned int)f2bf(xv[2]) | ((unsigned int)f2bf(xv[3]) << 16);
        unsigned int ya = (unsigned int)f2bf(yv[0]) | ((unsigned int)f2bf(yv[1]) << 16);
        unsigned int yb = (unsigned int)f2bf(yv[2]) | ((unsigned int)f2bf(yv[3]) << 16);
        U8 ub0, ub1;
        ub0.u[0] = (unsigned int)__shfl((int)xa, s0); ub0.u[1] = (unsigned int)__shfl((int)xb, s0);
        ub0.u[2] = (unsigned int)__shfl((int)xa, s1); ub0.u[3] = (unsigned int)__shfl((int)xb, s1);
        ub1.u[0] = (unsigned int)__shfl((int)ya, s0); ub1.u[1] = (unsigned int)__shfl((int)yb, s0);
        ub1.u[2] = (unsigned int)__shfl((int)ya, s1); ub1.u[3] = (unsigned int)__shfl((int)yb, s1);
        sB[(wave * 8 + 2 * t + 0) * 64 + lane] = ub0.s8;
        sB[(wave * 8 + 2 * t + 1) * 64 + lane] = ub1.s8;
    }
    __syncthreads();

    // VQ: this wave scans codes [wave*128, wave*128+128) against ALL 16 tiles
    unsigned int bk[16];
#pragma unroll
    for (int t = 0; t < 16; t++) bk[t] = 0u;
    int j0base = wave * 128;
#pragma unroll 2
    for (int jj = 0; jj < 8; jj++) {
        int j0 = j0base + jj * 16;
        short8 a0 = *(const short8*)(embbf + (j0 + l16) * 64 + quad * 8);
        short8 a1 = *(const short8*)(embbf + (j0 + l16) * 64 + 32 + quad * 8);
        f32x4 ci = *(const f32x4*)(hninit + j0 + quad * 4);
        int iv = 511 - j0 - quad * 4;
#pragma unroll
        for (int t = 0; t < 16; t++) {
            short8 vb0 = sB[(2 * t + 0) * 64 + lane];
            short8 vb1 = sB[(2 * t + 1) * 64 + lane];
            f32x4 s = __builtin_amdgcn_mfma_f32_16x16x32_bf16(a0, vb0, ci, 0, 0, 0);
            s = __builtin_amdgcn_mfma_f32_16x16x32_bf16(a1, vb1, s, 0, 0, 0);
#pragma unroll
            for (int r = 0; r < 4; r++) {
                unsigned int key = (__float_as_uint(s[r]) & 0xFFFFFE00u) | (unsigned int)(iv - r);
                bk[t] = bk[t] > key ? bk[t] : key;
            }
        }
    }
    // intra-wave reduce over the quad dimension -> per-pixel key (replicated x4)
#pragma unroll
    for (int t = 0; t < 16; t++) {
        unsigned int o1 = (unsigned int)__shfl_xor((int)bk[t], 16);
        bk[t] = bk[t] > o1 ? bk[t] : o1;
        unsigned int o2 = (unsigned int)__shfl_xor((int)bk[t], 32);
        bk[t] = bk[t] > o2 ? bk[t] : o2;
    }
    // cross-wave max via LDS: cross[(tile*16+px)*4 + wave]
    if (quad == 0) {
#pragma unroll
        for (int t = 0; t < 16; t++)
            cross[(t * 16 + l16) * 4 + wave] = bk[t];
    }
    __syncthreads();

    // epilogue: wave w owns row w = tiles 4w..4w+3
#pragma unroll
    for (int j = 0; j < 4; j++) {
        int tile = wave * 4 + j;
        uint4 k4 = *(const uint4*)(cross + (tile * 16 + l16) * 4);
        unsigned int key = k4.x > k4.y ? k4.x : k4.y;
        unsigned int k2 = k4.z > k4.w ? k4.z : k4.w;
        key = key > k2 ? key : k2;
        int code = 511 - (int)(key & 511u);
        int col = j * 16 + l16;
        int hw = oh * 64 + col;
        uint4 u0 = *(const uint4*)(embbf + code * 64 + quad * 16);
        uint4 u1 = *(const uint4*)(embbf + code * 64 + quad * 16 + 8);
        size_t qaddr = (size_t)n * 278784 + ((oh + 1) * 66 + (col + 1)) * 64 + quad * 16;
        *(uint4*)(zqp + qaddr) = u0;
        *(uint4*)(zqp + qaddr + 8) = u1;
        size_t zb = ((size_t)n * 64 + quad * 16) * 4096 + hw;
        unsigned int uw[8] = {u0.x, u0.y, u0.z, u0.w, u1.x, u1.y, u1.z, u1.w};
#pragma unroll
        for (int i = 0; i < 8; i++) {
            __builtin_nontemporal_store(__uint_as_float(uw[i] << 16), &zq_out[zb + (2 * i + 0) * 4096]);
            __builtin_nontemporal_store(__uint_as_float(uw[i] & 0xFFFF0000u), &zq_out[zb + (2 * i + 1) * 4096]);
        }
    }
}

// ---------------- d2 fused with d3 tap-score GEMM (shfl transform, no sT) ----------------
__global__ __launch_bounds__(256, 4) void k_d2f(const unsigned short* __restrict__ d1op,
                                                const unsigned short* __restrict__ apd2,
                                                const float* __restrict__ bias,
                                                const unsigned short* __restrict__ apd3,
                                                unsigned short* __restrict__ sc16) {
    __shared__ short8 sA[1024];                    // 16 KB (one parity's A)
    int tid = threadIdx.x;
    int wave = tid >> 6, lane = tid & 63, quad = lane >> 4, l16 = lane & 15;
    int bid = blockIdx.x;
    int n = bid >> 6, par = (bid >> 4) & 3, rg = bid & 15;
    int oh = rg * 4 + wave;
    int ph = par >> 1, pw = par & 1;

    short8 pa0 = ((const short8*)apd3)[lane];
    short8 pa1 = ((const short8*)apd3)[64 + lane];

    for (int i = tid; i < 1024; i += 256) sA[i] = ((const short8*)apd2)[par * 1024 + i];
    __syncthreads();

    int base0 = n * 139392 + ((oh + ph) * 66 + pw) * 32 + quad * 8;
    f32x4 acc[4][4];
#pragma unroll
    for (int t = 0; t < 4; t++)
#pragma unroll
        for (int mt = 0; mt < 4; mt++)
            acc[t][mt] = *(const f32x4*)(bias + mt * 16 + quad * 4);

#pragma unroll
    for (int k = 0; k < 4; k++) {
        int a_ = k >> 1, bb = k & 1;
        int off = (a_ * 66 + bb) * 32;
        short8 bfr[4];
#pragma unroll
        for (int t = 0; t < 4; t++)
            bfr[t] = *(const short8*)(d1op + base0 + (t * 16 + l16) * 32 + off);
#pragma unroll
        for (int mt = 0; mt < 4; mt++) {
            short8 a = sA[(k * 4 + mt) * 64 + lane];
#pragma unroll
            for (int t = 0; t < 4; t++)
                acc[t][mt] = __builtin_amdgcn_mfma_f32_16x16x32_bf16(a, bfr[t], acc[t][mt], 0, 0, 0);
        }
    }

    // relu + in-register transform + tap projection
    int s0 = (((2 * quad) & 3) << 4) | l16;
    int s1 = (((2 * quad + 1) & 3) << 4) | l16;
    int oh_out = 2 * oh + ph;
#pragma unroll
    for (int t = 0; t < 4; t++) {
#pragma unroll
        for (int mt = 0; mt < 4; mt++)
#pragma unroll
            for (int r = 0; r < 4; r++)
                acc[t][mt][r] = fmaxf(acc[t][mt][r], 0.f);
        f32x4 xv = (quad < 2) ? acc[t][0] : acc[t][1];
        f32x4 yv = (quad < 2) ? acc[t][2] : acc[t][3];
        unsigned int xa = (unsigned int)f2bf(xv[0]) | ((unsigned int)f2bf(xv[1]) << 16);
        unsigned int xb = (unsigned int)f2bf(xv[2]) | ((unsigned int)f2bf(xv[3]) << 16);
        unsigned int ya = (unsigned int)f2bf(yv[0]) | ((unsigned int)f2bf(yv[1]) << 16);
        unsigned int yb = (unsigned int)f2bf(yv[2]) | ((unsigned int)f2bf(yv[3]) << 16);
        U8 ub0, ub1;
        ub0.u[0] = (unsigned int)__shfl((int)xa, s0); ub0.u[1] = (unsigned int)__shfl((int)xb, s0);
        ub0.u[2] = (unsigned int)__shfl((int)xa, s1); ub0.u[3] = (unsigned int)__shfl((int)xb, s1);
        ub1.u[0] = (unsigned int)__shfl((int)ya, s0); ub1.u[1] = (unsigned int)__shfl((int)yb, s0);
        ub1.u[2] = (unsigned int)__shfl((int)ya, s1); ub1.u[3] = (unsigned int)__shfl((int)yb, s1);
        f32x4 sc = {0.f, 0.f, 0.f, 0.f};
        sc = __builtin_amdgcn_mfma_f32_16x16x32_bf16(pa0, ub0.s8, sc, 0, 0, 0);
        sc = __builtin_amdgcn_mfma_f32_16x16x32_bf16(pa1, ub1.s8, sc, 0, 0, 0);
        int ow_out = 2 * (t * 16 + l16) + pw;
        int pbaseo = n * 16384 + oh_out * 128 + ow_out;
#pragma unroll
        for (int r = 0; r < 4; r++) {
            int tap = quad * 4 + r;
            sc16[(size_t)tap * 1048576 + pbaseo] = f2bf(sc[r]);
        }
    }
}

// ---------------- d3 epilogue: gather 4 taps from tap-major bf16 planes ----------------
__global__ __launch_bounds__(256) void k_d3e(const unsigned short* __restrict__ sc16,
                                             const float* __restrict__ d3b,
                                             float* __restrict__ xhat) {
    int idx = blockIdx.x * 256 + threadIdx.x;
    int ow = idx & 255, oh = (idx >> 8) & 255, n = idx >> 16;
    float acc = d3b[0];
    int kh0 = (oh + 1) & 1, kw0 = (ow + 1) & 1;
#pragma unroll
    for (int dh = 0; dh < 2; dh++) {
        int kh = kh0 + 2 * dh;
        int ih = (oh + 1 - kh) >> 1;
        bool vh = ((unsigned)ih < 128u);
#pragma unroll
        for (int dw = 0; dw < 2; dw++) {
            int kw = kw0 + 2 * dw;
            int iw = (ow + 1 - kw) >> 1;
            if (vh && ((unsigned)iw < 128u))
                acc += bf2f(sc16[(size_t)(kh * 4 + kw) * 1048576 + n * 16384 + ih * 128 + iw]);
        }
    }
    __builtin_nontemporal_store(acc, &xhat[(size_t)n * 65536 + oh * 256 + ow]);
}

extern "C" void kernel_launch(void* const* d_in, const int* in_sizes, int n_in,
                              void* d_out, int out_size, void* d_ws, size_t ws_size,
                              hipStream_t stream) {
    const float* x    = (const float*)d_in[0];
    const float* e1w  = (const float*)d_in[1];
    const float* e1b  = (const float*)d_in[2];
    const float* e2w  = (const float*)d_in[3];
    const float* e2b  = (const float*)d_in[4];
    const float* e3w  = (const float*)d_in[5];
    const float* e3b  = (const float*)d_in[6];
    const float* emb  = (const float*)d_in[7];
    const float* d1w  = (const float*)d_in[8];
    const float* d1b  = (const float*)d_in[9];
    const float* d2w  = (const float*)d_in[10];
    const float* d2b  = (const float*)d_in[11];
    const float* d3w  = (const float*)d_in[12];
    const float* d3b  = (const float*)d_in[13];

    float* xhat = (float*)d_out;
    float* ze   = xhat + 4194304;
    float* zq   = ze + 16777216;

    char* ws = (char*)d_ws;
    unsigned short* h1p2   = (unsigned short*)(ws + 0);
    unsigned short* h2p    = (unsigned short*)(ws + 70287360);
    unsigned short* zqp    = (unsigned short*)(ws + 139526144);
    unsigned short* d1op   = (unsigned short*)(ws + 175210496);
    unsigned short* sc16   = (unsigned short*)(ws + 193052672);
    unsigned short* ape2   = (unsigned short*)(ws + 226607104);
    unsigned short* ape3   = (unsigned short*)(ws + 226672640);
    unsigned short* apd1   = (unsigned short*)(ws + 226746368);
    unsigned short* apd2   = (unsigned short*)(ws + 226783232);
    unsigned short* apd3   = (unsigned short*)(ws + 226848768);
    unsigned short* embbf  = (unsigned short*)(ws + 226850816);
    float*          hninit = (float*)(ws + 226916352);

    k_e1i<<<11454, 256, 0, stream>>>(x, e1w, e1b, h1p2, (unsigned int*)d_ws,
                                     e2w, e3w, d1w, d2w, d3w, emb,
                                     ape2, ape3, apd1, apd2, apd3, embbf, hninit);
    k_conv<32, 64, 16, 2, 0, 0><<<1024, 256, 0, stream>>>(h1p2, ape2, e2b, h2p);
    k_e3vq<<<1024, 256, 0, stream>>>(h2p, ape3, e3b, embbf, hninit, ze, zq, zqp);
    k_conv<64, 32, 18, 2, 66, 2><<<1024, 256, 0, stream>>>(zqp, apd1, d1b, d1op);
    k_d2f<<<4096, 256, 0, stream>>>(d1op, apd2, d2b, apd3, sc16);
    k_d3e<<<16384, 256, 0, stream>>>(sc16, d3b, xhat);
}

// Round 4
// 402.228 us; speedup vs baseline: 1.2725x; 1.2725x over previous
//
#include <hip/hip_runtime.h>

typedef short short8 __attribute__((ext_vector_type(8)));
typedef float f32x4 __attribute__((ext_vector_type(4)));

union U8 { short8 s8; unsigned int u[4]; };

__device__ __forceinline__ unsigned short f2bf(float f) {
    unsigned int u = __float_as_uint(f);
    u = (u + 0x7fffu + ((u >> 16) & 1u)) >> 16;
    return (unsigned short)u;
}
__device__ __forceinline__ float bf2f(unsigned short s) {
    return __uint_as_float(((unsigned int)s) << 16);
}

// ======== workspace byte offsets ========
// h1p2 : 0          (64,130,2,66,32) bf16  70,287,360 B  -- e1 out, parity-split cols
// h2p  : 70287360   (64,66,66,64)  bf16   35,684,352 B
// zqp  : 139526144  (64,66,66,64)  bf16   35,684,352 B
// d1op : 175210496  (64,66,66,32)  bf16   17,842,176 B
// sc16 : 193052672  (16,64,128,128) bf16  33,554,432 B  -- tap-major d3 scores
// ape2 : 226607104  65536 ; ape3: 226672640 73728 ; apd1: 226746368 36864
// apd2 : 226783232  65536 ; apd3: 226848768 2048  ; embbf: 226850816 65536
// hninit: 226916352 2048

// ---------------- e1 + halo zeroing + weight prep (single launch) ----------------
__global__ __launch_bounds__(256) void k_e1i(
    const float* __restrict__ x, const float* __restrict__ e1w, const float* __restrict__ e1b,
    unsigned short* __restrict__ h1p2, unsigned int* __restrict__ ws_dw,
    const float* __restrict__ e2w, const float* __restrict__ e3w,
    const float* __restrict__ d1w, const float* __restrict__ d2w,
    const float* __restrict__ d3w, const float* __restrict__ emb,
    unsigned short* __restrict__ ape2, unsigned short* __restrict__ ape3,
    unsigned short* __restrict__ apd1, unsigned short* __restrict__ apd2,
    unsigned short* __restrict__ apd3, unsigned short* __restrict__ embbf,
    float* __restrict__ hninit)
{
    int bid = blockIdx.x;
    if (bid < 4096) {
        // ---- e1 conv ----
        int idx = bid * 256 + threadIdx.x;
        int ow = idx & 127, oh = (idx >> 7) & 127, n = idx >> 14;
        const float* xn = x + (size_t)n * 65536;
        float patch[16];
#pragma unroll
        for (int kh = 0; kh < 4; kh++) {
            int ih = 2 * oh + kh - 1;
#pragma unroll
            for (int kw = 0; kw < 4; kw++) {
                int iw = 2 * ow + kw - 1;
                bool ok = ((unsigned)ih < 256u) & ((unsigned)iw < 256u);
                patch[kh * 4 + kw] = ok ? xn[ih * 256 + iw] : 0.f;
            }
        }
        unsigned int outw[16];
#pragma unroll
        for (int oc = 0; oc < 32; oc++) {
            float acc = e1b[oc];
#pragma unroll
            for (int t = 0; t < 16; t++) acc += patch[t] * e1w[oc * 16 + t];
            unsigned short bf = f2bf(fmaxf(acc, 0.f));
            if (oc & 1) outw[oc >> 1] |= ((unsigned int)bf) << 16;
            else        outw[oc >> 1] = bf;
        }
        int par = ow & 1;
        int cidx = (ow + par) >> 1;
        size_t base = ((size_t)((idx >> 14) * 130 + oh + 1) * 2 + par) * 2112 + cidx * 32;
        uint4* dst = (uint4*)(h1p2 + base);
#pragma unroll
        for (int i = 0; i < 4; i++) dst[i] = *(uint4*)&outw[i * 4];
        return;
    }
    if (bid < 11376) {
        // ---- halo zeroing ----
        int t = (bid - 4096) * 256 + threadIdx.x;
        if (t < 270336) {
            int img = t / 4224, q = t % 4224;
            int rowsel = q / 2112, rem = q % 2112;
            ws_dw[img * 274560 + rowsel * 129 * 2112 + rem] = 0u;
        } else if (t < 532480) {
            int g = t - 270336;
            int img = g / 4096, q = g % 4096;
            int row = 1 + (q >> 5), c2 = q & 31;
            int sel = c2 >> 4, ch = c2 & 15;
            int par = sel ? 0 : 1, idx2 = sel ? 64 : 0;
            ws_dw[img * 274560 + row * 2112 + par * 1056 + idx2 * 16 + ch] = 0u;
        } else if (t < 1863680) {
            unsigned int base, Cd, r;
            if (t < 1064960)      { base = 17571840u; Cd = 32; r = t - 532480;  }   // h2p
            else if (t < 1597440) { base = 34881536u; Cd = 32; r = t - 1064960; }   // zqp
            else                  { base = 43802624u; Cd = 16; r = t - 1597440; }   // d1op
            unsigned int per_img = 260u * Cd;
            unsigned int img = r / per_img, q = r % per_img;
            unsigned int p = q / Cd, c = q % Cd;
            unsigned int row, col;
            if (p < 66u)        { row = 0;  col = p; }
            else if (p < 132u)  { row = 65; col = p - 66u; }
            else { unsigned int s = p - 132u; row = 1 + (s >> 1); col = (s & 1) ? 65u : 0u; }
            ws_dw[base + ((img * 66u + row) * 66u + col) * Cd + c] = 0u;
        }
        return;
    }
    // ---- weight prep ----
    int f = (bid - 11376) * 256 + threadIdx.x;
    if (f < 4096) {                               // e2
        int ks = f >> 8, mt = (f >> 6) & 3, lane = f & 63;
        int quad = lane >> 4, l16 = lane & 15;
        int oc = mt * 16 + l16, kh = ks >> 2, kw = ks & 3;
        short8 sv;
#pragma unroll
        for (int j = 0; j < 8; j++) {
            int ic = quad * 8 + j;
            sv[j] = (short)f2bf(e2w[((oc * 32 + ic) * 4 + kh) * 4 + kw]);
        }
        ((short8*)ape2)[f] = sv;
    } else if (f < 8704) {                        // e3
        int g = f - 4096;
        int ks = g >> 8, mt = (g >> 6) & 3, lane = g & 63;
        int quad = lane >> 4, l16 = lane & 15;
        int oc = mt * 16 + l16, tap = ks >> 1, kh = tap / 3, kw = tap % 3;
        int icb = (ks & 1) * 32 + quad * 8;
        short8 sv;
#pragma unroll
        for (int j = 0; j < 8; j++)
            sv[j] = (short)f2bf(e3w[((oc * 64 + icb + j) * 3 + kh) * 3 + kw]);
        ((short8*)ape3)[g] = sv;
    } else if (f < 11008) {                       // d1 (flipped)
        int g = f - 8704;
        int ks = g >> 7, mt = (g >> 6) & 1, lane = g & 63;
        int quad = lane >> 4, l16 = lane & 15;
        int oc = mt * 16 + l16, tap = ks >> 1, kh = tap / 3, kw = tap % 3;
        int icb = (ks & 1) * 32 + quad * 8;
        short8 sv;
#pragma unroll
        for (int j = 0; j < 8; j++)
            sv[j] = (short)f2bf(d1w[(((icb + j) * 32 + oc) * 3 + (2 - kh)) * 3 + (2 - kw)]);
        ((short8*)apd1)[g] = sv;
    } else if (f < 15104) {                       // d2 per parity
        int g = f - 11008;
        int par = g >> 10, ks = (g >> 8) & 3, mt = (g >> 6) & 3, lane = g & 63;
        int quad = lane >> 4, l16 = lane & 15;
        int ph = par >> 1, pw = par & 1, a = ks >> 1, bb = ks & 1;
        int kh = 3 - ph - 2 * a, kw = 3 - pw - 2 * bb;
        int oc = mt * 16 + l16;
        short8 sv;
#pragma unroll
        for (int j = 0; j < 8; j++) {
            int ic = quad * 8 + j;
            sv[j] = (short)f2bf(d2w[((ic * 64 + oc) * 4 + kh) * 4 + kw]);
        }
        ((short8*)apd2)[g] = sv;
    } else if (f < 15232) {                       // d3: A[tap][ic]
        int g = f - 15104;
        int ks = g >> 6, lane = g & 63;
        int quad = lane >> 4, tap = lane & 15;
        short8 sv;
#pragma unroll
        for (int j = 0; j < 8; j++) {
            int ic = ks * 32 + quad * 8 + j;
            sv[j] = (short)f2bf(d3w[ic * 16 + tap]);
        }
        ((short8*)apd3)[g] = sv;
    } else if (f < 19328) {                       // emb bf16
        int g = f - 15232;
        int code = g >> 3, chb = (g & 7) * 8;
        short8 sv;
#pragma unroll
        for (int j = 0; j < 8; j++) sv[j] = (short)f2bf(emb[code * 64 + chb + j]);
        ((short8*)embbf)[g] = sv;
    } else if (f < 19840) {                       // hninit = 2 - 0.5||e||^2
        int code = f - 19328;
        float s = 0.f;
        for (int c = 0; c < 64; c++) { float v = emb[code * 64 + c]; s += v * v; }
        hninit[code] = 2.0f - 0.5f * s;
    }
}

// ---------------- MFMA implicit-GEMM conv ----------------
// MODE 0: e2 (parity-split input)   2: d1
template<int CIN, int COUT, int KSTEPS, int NCH, int WPIN, int MODE>
__global__ __launch_bounds__(256, 4) void k_conv(const unsigned short* __restrict__ inp,
                                                 const unsigned short* __restrict__ aprep,
                                                 const float* __restrict__ bias,
                                                 unsigned short* __restrict__ out0) {
    constexpr int MT = COUT / 16;
    constexpr int KCH = KSTEPS / NCH;
    __shared__ short8 sA[KCH * MT * 64];
    int tid = threadIdx.x;
    int wave = tid >> 6, lane = tid & 63, quad = lane >> 4, l16 = lane & 15;
    int bid = blockIdx.x;
    int n = bid >> 4, rg = bid & 15;
    int oh = rg * 4 + wave;

    int base0;
    if (MODE == 0) base0 = (n * 130 + 2 * oh) * 4224 + quad * 8;
    else           base0 = n * (WPIN * WPIN * CIN) + ((oh + 1) * WPIN + 1) * CIN + quad * 8;

    f32x4 acc[4][MT];
#pragma unroll
    for (int t = 0; t < 4; t++)
#pragma unroll
        for (int mt = 0; mt < MT; mt++)
            acc[t][mt] = *(const f32x4*)(bias + mt * 16 + quad * 4);

#pragma unroll
    for (int ch = 0; ch < NCH; ch++) {
        for (int i = tid; i < KCH * MT * 64; i += 256)
            sA[i] = ((const short8*)aprep)[ch * (KCH * MT * 64) + i];
        __syncthreads();
#pragma unroll
        for (int k = 0; k < KCH; k++) {
            int ks = ch * KCH + k;
            int off, pxs;
            if (MODE == 0) {
                int kh = ks >> 2, kw = ks & 3;
                int par = (kw & 1) ^ 1;
                off = kh * 4224 + par * 2112 + (kw >> 1) * 32;
                pxs = 32;
            } else {
                int tap = ks >> 1, kh = tap / 3, kw = tap % 3;
                off = ((kh - 1) * WPIN + (kw - 1)) * CIN + (ks & 1) * 32;
                pxs = CIN;
            }
            short8 bfr[4];
#pragma unroll
            for (int t = 0; t < 4; t++)
                bfr[t] = *(const short8*)(inp + base0 + (t * 16 + l16) * pxs + off);
#pragma unroll
            for (int mt = 0; mt < MT; mt++) {
                short8 a = sA[(k * MT + mt) * 64 + lane];
#pragma unroll
                for (int t = 0; t < 4; t++)
                    acc[t][mt] = __builtin_amdgcn_mfma_f32_16x16x32_bf16(a, bfr[t], acc[t][mt], 0, 0, 0);
            }
        }
        if (ch + 1 < NCH) __syncthreads();
    }

#pragma unroll
    for (int t = 0; t < 4; t++) {
        int ow = t * 16 + l16;
#pragma unroll
        for (int mt = 0; mt < MT; mt++) {
            float v0 = fmaxf(acc[t][mt][0], 0.f), v1 = fmaxf(acc[t][mt][1], 0.f);
            float v2 = fmaxf(acc[t][mt][2], 0.f), v3 = fmaxf(acc[t][mt][3], 0.f);
            unsigned int lo = (unsigned int)f2bf(v0) | ((unsigned int)f2bf(v1) << 16);
            unsigned int hi = (unsigned int)f2bf(v2) | ((unsigned int)f2bf(v3) << 16);
            uint2 uu; uu.x = lo; uu.y = hi;
            int oc = mt * 16 + quad * 4;
            if (MODE == 0) {
                size_t addr = (size_t)n * 278784 + ((oh + 1) * 66 + ow + 1) * 64 + oc;
                *(uint2*)(out0 + addr) = uu;
            } else {
                size_t addr = (size_t)n * 139392 + ((oh + 1) * 66 + ow + 1) * 32 + oc;
                *(uint2*)(out0 + addr) = uu;
            }
        }
    }
}

// ---------------- e3 conv fused with VQ ----------------
// R4: R1 structure (pixel-partitioned tiles, bk[4], acc[4][4], grid 1024; 102us)
// + LDS-staged codebook. R3's register-partition spilled (bk[16] > 64 arch-VGPR
// budget: +388MB scratch HBM traffic). Instead share the codebook stream through
// LDS: stage 16KB chunks (128 codes) in the dead sA region; all 4 waves scan the
// chunk against their own 4 tiles. Per-block codebook L2 traffic 256KB -> 64KB.
// Chunk rows XOR-swizzled (slot ^= row&7): unswizzled, each quad's 16 lanes hit
// one 4-bank group (2x the b128 floor); swizzled = 8 lanes/group = at the floor.
__global__ __launch_bounds__(256, 4) void k_e3vq(const unsigned short* __restrict__ h2p,
                                                 const unsigned short* __restrict__ ape3,
                                                 const float* __restrict__ bias,
                                                 const unsigned short* __restrict__ embbf,
                                                 const float* __restrict__ hninit,
                                                 float* __restrict__ ze_out,
                                                 float* __restrict__ zq_out,
                                                 unsigned short* __restrict__ zqp) {
    __shared__ __align__(16) char smem[36864];
    short8* sA = (short8*)smem;            // conv phase: 2304 short8 = 36KB
    char*   sC = smem;                     // VQ phase: 16KB swizzled codebook chunk

    int tid = threadIdx.x;
    int wave = tid >> 6, lane = tid & 63, quad = lane >> 4, l16 = lane & 15;
    int bid = blockIdx.x;
    int n = bid >> 4, rg = bid & 15;
    int oh = rg * 4 + wave;
    int base0 = n * 278784 + ((oh + 1) * 66 + 1) * 64 + quad * 8;

    f32x4 acc[4][4];
#pragma unroll
    for (int t = 0; t < 4; t++)
#pragma unroll
        for (int mt = 0; mt < 4; mt++)
            acc[t][mt] = *(const f32x4*)(bias + mt * 16 + quad * 4);

#pragma unroll
    for (int ch = 0; ch < 2; ch++) {
        for (int i = tid; i < 9 * 4 * 64; i += 256)
            sA[i] = ((const short8*)ape3)[ch * (9 * 4 * 64) + i];
        __syncthreads();
#pragma unroll
        for (int k = 0; k < 9; k++) {
            int ks = ch * 9 + k;
            int tap = ks >> 1, kh = tap / 3, kw = tap % 3;
            int off = ((kh - 1) * 66 + (kw - 1)) * 64 + (ks & 1) * 32;
            short8 bfr[4];
#pragma unroll
            for (int t = 0; t < 4; t++)
                bfr[t] = *(const short8*)(h2p + base0 + (t * 16 + l16) * 64 + off);
#pragma unroll
            for (int mt = 0; mt < 4; mt++) {
                short8 a = sA[(k * 4 + mt) * 64 + lane];
#pragma unroll
                for (int t = 0; t < 4; t++)
                    acc[t][mt] = __builtin_amdgcn_mfma_f32_16x16x32_bf16(a, bfr[t], acc[t][mt], 0, 0, 0);
            }
        }
        if (ch == 0) __syncthreads();
    }

    // relu in place
#pragma unroll
    for (int t = 0; t < 4; t++)
#pragma unroll
        for (int mt = 0; mt < 4; mt++)
#pragma unroll
            for (int r = 0; r < 4; r++)
                acc[t][mt][r] = fmaxf(acc[t][mt][r], 0.f);

    // ze fp32 NCHW (graded output), nontemporal
#pragma unroll
    for (int t = 0; t < 4; t++) {
        int px = oh * 64 + t * 16 + l16;
#pragma unroll
        for (int mt = 0; mt < 4; mt++) {
            int oc = mt * 16 + quad * 4;
#pragma unroll
            for (int r = 0; r < 4; r++)
                __builtin_nontemporal_store(acc[t][mt][r], &ze_out[((size_t)n * 64 + oc + r) * 4096 + px]);
        }
    }

    // in-register C-layout -> B-layout transform (8 shfl per tile)
    short8 b0[4], b1[4];
    int s0 = (((2 * quad) & 3) << 4) | l16;
    int s1 = (((2 * quad + 1) & 3) << 4) | l16;
#pragma unroll
    for (int t = 0; t < 4; t++) {
        f32x4 xv = (quad < 2) ? acc[t][0] : acc[t][1];
        f32x4 yv = (quad < 2) ? acc[t][2] : acc[t][3];
        unsigned int xa = (unsigned int)f2bf(xv[0]) | ((unsigned int)f2bf(xv[1]) << 16);
        unsigned int xb = (unsigned int)f2bf(xv[2]) | ((unsigned int)f2bf(xv[3]) << 16);
        unsigned int ya = (unsigned int)f2bf(yv[0]) | ((unsigned int)f2bf(yv[1]) << 16);
        unsigned int yb = (unsigned int)f2bf(yv[2]) | ((unsigned int)f2bf(yv[3]) << 16);
        U8 ub0, ub1;
        ub0.u[0] = (unsigned int)__shfl((int)xa, s0); ub0.u[1] = (unsigned int)__shfl((int)xb, s0);
        ub0.u[2] = (unsigned int)__shfl((int)xa, s1); ub0.u[3] = (unsigned int)__shfl((int)xb, s1);
        ub1.u[0] = (unsigned int)__shfl((int)ya, s0); ub1.u[1] = (unsigned int)__shfl((int)yb, s0);
        ub1.u[2] = (unsigned int)__shfl((int)ya, s1); ub1.u[3] = (unsigned int)__shfl((int)yb, s1);
        b0[t] = ub0.s8; b1[t] = ub1.s8;
    }

    // VQ: 4 chunks of 128 codes staged through LDS, packed-key argmax (bit-exact
    // same key set as the R1 global-stream version).
    unsigned int bk[4] = {0u, 0u, 0u, 0u};
#pragma unroll 1
    for (int cb = 0; cb < 4; cb++) {
        __syncthreads();                   // prior chunk (or conv sA) fully consumed
        {
            int r = tid >> 1, h = tid & 1;
            const uint4* src = (const uint4*)embbf;    // uint4 = 8 shorts
#pragma unroll
            for (int i = 0; i < 4; i++) {
                uint4 v = src[cb * 1024 + tid * 4 + i];
                int slot = 4 * h + i;
                *(uint4*)(sC + r * 128 + ((slot ^ (r & 7)) << 4)) = v;
            }
        }
        __syncthreads();
#pragma unroll 2
        for (int jj = 0; jj < 8; jj++) {
            int j0 = cb * 128 + jj * 16;
            int rr = jj * 16 + l16;
            int sw = (rr & 7) << 4;
            short8 a0 = *(const short8*)(sC + rr * 128 + (((quad << 4)) ^ sw));
            short8 a1 = *(const short8*)(sC + rr * 128 + ((((quad + 4) << 4)) ^ sw));
            f32x4 ci = *(const f32x4*)(hninit + j0 + quad * 4);
            int iv = 511 - j0 - quad * 4;
#pragma unroll
            for (int t = 0; t < 4; t++) {
                f32x4 s = __builtin_amdgcn_mfma_f32_16x16x32_bf16(a0, b0[t], ci, 0, 0, 0);
                s = __builtin_amdgcn_mfma_f32_16x16x32_bf16(a1, b1[t], s, 0, 0, 0);
#pragma unroll
                for (int r = 0; r < 4; r++) {
                    unsigned int key = (__float_as_uint(s[r]) & 0xFFFFFE00u) | (unsigned int)(iv - r);
                    bk[t] = bk[t] > key ? bk[t] : key;
                }
            }
        }
    }
#pragma unroll
    for (int t = 0; t < 4; t++) {
        unsigned int o1 = (unsigned int)__shfl_xor((int)bk[t], 16);
        bk[t] = bk[t] > o1 ? bk[t] : o1;
        unsigned int o2 = (unsigned int)__shfl_xor((int)bk[t], 32);
        bk[t] = bk[t] > o2 ? bk[t] : o2;
    }
#pragma unroll
    for (int t = 0; t < 4; t++) {
        int code = 511 - (int)(bk[t] & 511u);
        int col = t * 16 + l16;
        int hw = oh * 64 + col;
        uint4 u0 = *(const uint4*)(embbf + code * 64 + quad * 16);
        uint4 u1 = *(const uint4*)(embbf + code * 64 + quad * 16 + 8);
        size_t qaddr = (size_t)n * 278784 + ((oh + 1) * 66 + (col + 1)) * 64 + quad * 16;
        *(uint4*)(zqp + qaddr) = u0;
        *(uint4*)(zqp + qaddr + 8) = u1;
        size_t zb = ((size_t)n * 64 + quad * 16) * 4096 + hw;
        unsigned int uw[8] = {u0.x, u0.y, u0.z, u0.w, u1.x, u1.y, u1.z, u1.w};
#pragma unroll
        for (int i = 0; i < 8; i++) {
            __builtin_nontemporal_store(__uint_as_float(uw[i] << 16), &zq_out[zb + (2 * i + 0) * 4096]);
            __builtin_nontemporal_store(__uint_as_float(uw[i] & 0xFFFF0000u), &zq_out[zb + (2 * i + 1) * 4096]);
        }
    }
}

// ---------------- d2 fused with d3 tap-score GEMM (shfl transform, no sT) ----------------
__global__ __launch_bounds__(256, 4) void k_d2f(const unsigned short* __restrict__ d1op,
                                                const unsigned short* __restrict__ apd2,
                                                const float* __restrict__ bias,
                                                const unsigned short* __restrict__ apd3,
                                                unsigned short* __restrict__ sc16) {
    __shared__ short8 sA[1024];                    // 16 KB (one parity's A)
    int tid = threadIdx.x;
    int wave = tid >> 6, lane = tid & 63, quad = lane >> 4, l16 = lane & 15;
    int bid = blockIdx.x;
    int n = bid >> 6, par = (bid >> 4) & 3, rg = bid & 15;
    int oh = rg * 4 + wave;
    int ph = par >> 1, pw = par & 1;

    short8 pa0 = ((const short8*)apd3)[lane];
    short8 pa1 = ((const short8*)apd3)[64 + lane];

    for (int i = tid; i < 1024; i += 256) sA[i] = ((const short8*)apd2)[par * 1024 + i];
    __syncthreads();

    int base0 = n * 139392 + ((oh + ph) * 66 + pw) * 32 + quad * 8;
    f32x4 acc[4][4];
#pragma unroll
    for (int t = 0; t < 4; t++)
#pragma unroll
        for (int mt = 0; mt < 4; mt++)
            acc[t][mt] = *(const f32x4*)(bias + mt * 16 + quad * 4);

#pragma unroll
    for (int k = 0; k < 4; k++) {
        int a_ = k >> 1, bb = k & 1;
        int off = (a_ * 66 + bb) * 32;
        short8 bfr[4];
#pragma unroll
        for (int t = 0; t < 4; t++)
            bfr[t] = *(const short8*)(d1op + base0 + (t * 16 + l16) * 32 + off);
#pragma unroll
        for (int mt = 0; mt < 4; mt++) {
            short8 a = sA[(k * 4 + mt) * 64 + lane];
#pragma unroll
            for (int t = 0; t < 4; t++)
                acc[t][mt] = __builtin_amdgcn_mfma_f32_16x16x32_bf16(a, bfr[t], acc[t][mt], 0, 0, 0);
        }
    }

    // relu + in-register transform + tap projection
    int s0 = (((2 * quad) & 3) << 4) | l16;
    int s1 = (((2 * quad + 1) & 3) << 4) | l16;
    int oh_out = 2 * oh + ph;
#pragma unroll
    for (int t = 0; t < 4; t++) {
#pragma unroll
        for (int mt = 0; mt < 4; mt++)
#pragma unroll
            for (int r = 0; r < 4; r++)
                acc[t][mt][r] = fmaxf(acc[t][mt][r], 0.f);
        f32x4 xv = (quad < 2) ? acc[t][0] : acc[t][1];
        f32x4 yv = (quad < 2) ? acc[t][2] : acc[t][3];
        unsigned int xa = (unsigned int)f2bf(xv[0]) | ((unsigned int)f2bf(xv[1]) << 16);
        unsigned int xb = (unsigned int)f2bf(xv[2]) | ((unsigned int)f2bf(xv[3]) << 16);
        unsigned int ya = (unsigned int)f2bf(yv[0]) | ((unsigned int)f2bf(yv[1]) << 16);
        unsigned int yb = (unsigned int)f2bf(yv[2]) | ((unsigned int)f2bf(yv[3]) << 16);
        U8 ub0, ub1;
        ub0.u[0] = (unsigned int)__shfl((int)xa, s0); ub0.u[1] = (unsigned int)__shfl((int)xb, s0);
        ub0.u[2] = (unsigned int)__shfl((int)xa, s1); ub0.u[3] = (unsigned int)__shfl((int)xb, s1);
        ub1.u[0] = (unsigned int)__shfl((int)ya, s0); ub1.u[1] = (unsigned int)__shfl((int)yb, s0);
        ub1.u[2] = (unsigned int)__shfl((int)ya, s1); ub1.u[3] = (unsigned int)__shfl((int)yb, s1);
        f32x4 sc = {0.f, 0.f, 0.f, 0.f};
        sc = __builtin_amdgcn_mfma_f32_16x16x32_bf16(pa0, ub0.s8, sc, 0, 0, 0);
        sc = __builtin_amdgcn_mfma_f32_16x16x32_bf16(pa1, ub1.s8, sc, 0, 0, 0);
        int ow_out = 2 * (t * 16 + l16) + pw;
        int pbaseo = n * 16384 + oh_out * 128 + ow_out;
#pragma unroll
        for (int r = 0; r < 4; r++) {
            int tap = quad * 4 + r;
            sc16[(size_t)tap * 1048576 + pbaseo] = f2bf(sc[r]);
        }
    }
}

// ---------------- d3 epilogue: gather 4 taps from tap-major bf16 planes ----------------
__global__ __launch_bounds__(256) void k_d3e(const unsigned short* __restrict__ sc16,
                                             const float* __restrict__ d3b,
                                             float* __restrict__ xhat) {
    int idx = blockIdx.x * 256 + threadIdx.x;
    int ow = idx & 255, oh = (idx >> 8) & 255, n = idx >> 16;
    float acc = d3b[0];
    int kh0 = (oh + 1) & 1, kw0 = (ow + 1) & 1;
#pragma unroll
    for (int dh = 0; dh < 2; dh++) {
        int kh = kh0 + 2 * dh;
        int ih = (oh + 1 - kh) >> 1;
        bool vh = ((unsigned)ih < 128u);
#pragma unroll
        for (int dw = 0; dw < 2; dw++) {
            int kw = kw0 + 2 * dw;
            int iw = (ow + 1 - kw) >> 1;
            if (vh && ((unsigned)iw < 128u))
                acc += bf2f(sc16[(size_t)(kh * 4 + kw) * 1048576 + n * 16384 + ih * 128 + iw]);
        }
    }
    __builtin_nontemporal_store(acc, &xhat[(size_t)n * 65536 + oh * 256 + ow]);
}

extern "C" void kernel_launch(void* const* d_in, const int* in_sizes, int n_in,
                              void* d_out, int out_size, void* d_ws, size_t ws_size,
                              hipStream_t stream) {
    const float* x    = (const float*)d_in[0];
    const float* e1w  = (const float*)d_in[1];
    const float* e1b  = (const float*)d_in[2];
    const float* e2w  = (const float*)d_in[3];
    const float* e2b  = (const float*)d_in[4];
    const float* e3w  = (const float*)d_in[5];
    const float* e3b  = (const float*)d_in[6];
    const float* emb  = (const float*)d_in[7];
    const float* d1w  = (const float*)d_in[8];
    const float* d1b  = (const float*)d_in[9];
    const float* d2w  = (const float*)d_in[10];
    const float* d2b  = (const float*)d_in[11];
    const float* d3w  = (const float*)d_in[12];
    const float* d3b  = (const float*)d_in[13];

    float* xhat = (float*)d_out;
    float* ze   = xhat + 4194304;
    float* zq   = ze + 16777216;

    char* ws = (char*)d_ws;
    unsigned short* h1p2   = (unsigned short*)(ws + 0);
    unsigned short* h2p    = (unsigned short*)(ws + 70287360);
    unsigned short* zqp    = (unsigned short*)(ws + 139526144);
    unsigned short* d1op   = (unsigned short*)(ws + 175210496);
    unsigned short* sc16   = (unsigned short*)(ws + 193052672);
    unsigned short* ape2   = (unsigned short*)(ws + 226607104);
    unsigned short* ape3   = (unsigned short*)(ws + 226672640);
    unsigned short* apd1   = (unsigned short*)(ws + 226746368);
    unsigned short* apd2   = (unsigned short*)(ws + 226783232);
    unsigned short* apd3   = (unsigned short*)(ws + 226848768);
    unsigned short* embbf  = (unsigned short*)(ws + 226850816);
    float*          hninit = (float*)(ws + 226916352);

    k_e1i<<<11454, 256, 0, stream>>>(x, e1w, e1b, h1p2, (unsigned int*)d_ws,
                                     e2w, e3w, d1w, d2w, d3w, emb,
                                     ape2, ape3, apd1, apd2, apd3, embbf, hninit);
    k_conv<32, 64, 16, 2, 0, 0><<<1024, 256, 0, stream>>>(h1p2, ape2, e2b, h2p);
    k_e3vq<<<1024, 256, 0, stream>>>(h2p, ape3, e3b, embbf, hninit, ze, zq, zqp);
    k_conv<64, 32, 18, 2, 66, 2><<<1024, 256, 0, stream>>>(zqp, apd1, d1b, d1op);
    k_d2f<<<4096, 256, 0, stream>>>(d1op, apd2, d2b, apd3, sc16);
    k_d3e<<<16384, 256, 0, stream>>>(sc16, d3b, xhat);
}